// Round 11
// baseline (102.806 us; speedup 1.0000x reference)
//
#include <hip/hip_runtime.h>
#include <math.h>

#define N_FILT 64
#define IMG_DIM 256
#define IMG_SZ (256*256)
#define HDIM 1024
#define NBATCH 512

typedef __attribute__((ext_vector_type(4))) float f32x4;
typedef __attribute__((address_space(3))) float lds_float;

// ws layout (131,328 B total):
//   int meta[64]: [0..15]=loY [16..31]=hiY     (16 n-groups of 4, stage 1)
//                 [32..47]=lo4X (granule-aligned) [48..63]=hiX (16 m-groups of 4)
//   byte 256           : fyg [16][256][4] float, ABSOLUTE row index,
//                        (gamma/SY folded, zero outside band)          64 KiB
//   byte 256+65536     : fxg [16][256][4] float (1/SX folded, packed from lo4,
//                        zero-filled)                                   64 KiB

// async DMA: one wave-issue copies 64 lanes x 16B = 1KB row into LDS at
// wave-uniform base + lane*16 (gfx950 global_load_lds_dwordx4).
__device__ __forceinline__ void gl_lds16(const float* g, float* l){
  __builtin_amdgcn_global_load_lds(
      (const __attribute__((address_space(1))) unsigned int*)g,
      (__attribute__((address_space(3))) unsigned int*)l,
      16, 0, 0);
}

// grid = 2: block 0 builds the Y side (fyg), block 1 the X side (fxg).
__global__ __launch_bounds__(256) void k_prep(
    const float* __restrict__ h, const float* __restrict__ Ww,
    const float* __restrict__ Wb, int* __restrict__ meta,
    float* __restrict__ fyg, float* __restrict__ fxg)
{
  __shared__ float partial[32];      // [wave][slot]
  __shared__ float par_s[8];
  __shared__ float F[N_FILT*IMG_DIM];
  __shared__ int s_lo[64], s_hi[64], s_glo[16], s_ghi[16];
  __shared__ float ssum[4];
  const int t   = threadIdx.x;
  const int side= blockIdx.x;        // 0=Y, 1=X
  const int wv  = t>>6, ln = t&63;
  float* __restrict__ wout = side ? fxg : fyg;

  // zero-fill this side's weight buffer (packs only overwrite in-band rows)
  {
    float4 z = make_float4(0.f,0.f,0.f,0.f);
    float4* p = (float4*)wout;
    #pragma unroll
    for (int k=0;k<16;++k) p[t + 256*k] = z;
  }

  // ---- params[j] = h[0] . W_read_w[j] + W_read_b[j] (single pass over h) ----
  {
    float s0=0.f,s1=0.f,s2=0.f,s3=0.f,s4=0.f;
    for (int k=t;k<HDIM;k+=256){
      const float hv=h[k];
      s0=fmaf(hv,Ww[k        ],s0);
      s1=fmaf(hv,Ww[HDIM+k   ],s1);
      s2=fmaf(hv,Ww[2*HDIM+k ],s2);
      s3=fmaf(hv,Ww[3*HDIM+k ],s3);
      s4=fmaf(hv,Ww[4*HDIM+k ],s4);
    }
    #pragma unroll
    for (int o=32;o>0;o>>=1){
      s0+=__shfl_down(s0,o); s1+=__shfl_down(s1,o); s2+=__shfl_down(s2,o);
      s3+=__shfl_down(s3,o); s4+=__shfl_down(s4,o);
    }
    if (ln==0){ partial[wv*8+0]=s0; partial[wv*8+1]=s1; partial[wv*8+2]=s2;
                partial[wv*8+3]=s3; partial[wv*8+4]=s4; }
  }
  __syncthreads();
  if (t<5) par_s[t]=partial[t]+partial[8+t]+partial[16+t]+partial[24+t]+Wb[t];
  __syncthreads();

  const float var   = expf(par_s[2]+1e-8f);
  const float dt    = expf(par_s[3]);
  const float gamma = expf(par_s[4]);
  const float gC = 0.5f*257.f*(par_s[side?0:1]+1.f);  // Y<-par[1], X<-par[0]
  const float d  = dt*(255.f/63.f);
  const float sub= -32.5f*d;
  const float inv2v = 1.f/(2.f*var);
  const float w88v  = 88.f*var;   // band cutoff: e(a)/e(peak) >= exp(-44)

  if (t<64){
    float mu = gC + sub + d*(float)t;
    float astar = fminf(255.f, fmaxf(0.f, rintf(mu)));   // clamped peak
    float t0 = (astar-mu)*(astar-mu);
    float r  = sqrtf(t0 + w88v);
    int lo = (int)ceilf(mu-r); int hi = (int)floorf(mu+r)+1;
    lo = lo<0?0:lo; hi = hi>256?256:hi; if (hi<lo) hi=lo;
    s_lo[t]=lo; s_hi[t]=hi;
  }
  __syncthreads();
  if (t<16){
    int lo=256, hi=0;
    #pragma unroll
    for (int k2=0;k2<4;++k2){ lo=min(lo,s_lo[t*4+k2]); hi=max(hi,s_hi[t*4+k2]); }
    if (hi<lo){lo=0;hi=0;}
    if (side==0){ meta[t]=lo; meta[16+t]=hi; }
    else        { lo &= ~3;  meta[32+t]=lo; meta[48+t]=hi; }  // granule-aligned
    s_glo[t]=lo; s_ghi[t]=hi;
  }
  // F + global sum
  float sum=0.f;
  #pragma unroll
  for (int k=0;k<64;++k){
    int idx=t+256*k;
    int n=idx>>8, a=idx&255;
    float mu = gC+sub+d*(float)n;
    float dx=(float)a-mu;
    float e=expf(-dx*dx*inv2v);
    F[idx]=e; sum+=e;
  }
  #pragma unroll
  for (int o=32;o>0;o>>=1) sum+=__shfl_down(sum,o);
  if (ln==0) ssum[wv]=sum;
  __syncthreads();
  const float stot = ssum[0]+ssum[1]+ssum[2]+ssum[3];
  const float sc = (side==0 ? gamma : 1.f)/stot;   // fold gamma into Y side
  #pragma unroll
  for (int k=0;k<64;++k){
    int idx=t+256*k;
    int n=idx>>8, a=idx&255, g=n>>2;
    int lo=s_glo[g], hi=s_ghi[g];
    if (a>=lo && a<hi){
      // Y side: ABSOLUTE row index (ring kernel); X side: packed from lo4
      const int row = side ? (a-lo) : a;
      wout[(size_t)((g<<10)+(row<<2)+(n&3))] = F[idx]*sc;
    }
  }
}

// 4096 blocks: 4 blocks per image (16 filters each). 4 waves; wave w owns
// stage-1 n-group g=qq*4+w and stage-2 m-group q=w*4+(lane>>4).
// Stage 1: wave-private ring (4 slots x 1 row) of global_load_lds DMAs,
// constant clobber-free s_waitcnt vmcnt(3) (depth 3 = 3KB/wave in flight),
// ZERO non-DMA VMEM in the loop (weights pre-staged in LDS -> lgkm domain),
// no barriers in the loop. Rule-18 consume: asm ds_read + lgkmcnt(0) + SB0.
__global__ __launch_bounds__(256, 5) void k_main(
    const float* __restrict__ x, const float* __restrict__ xh,
    const int* __restrict__ meta, const float* __restrict__ fyg,
    const float* __restrict__ fxg, float* __restrict__ out)
{
  __shared__ float RING[4][4][256];  // [wave][slot][cols] = 16 KiB
  __shared__ float SW[4][1024];      // [wave][256 rows x 4 filters] = 16 KiB
  float* const TT = &RING[0][0][0];  // Tt[16][256] overlays the ring later
  const int bid = blockIdx.x;
  const int lg  = ((bid&7)<<9) | (bid>>3);   // same-image quads -> same XCD
  const int img = lg>>2, qq = lg&3;
  const int tid = threadIdx.x;
  const int w    = __builtin_amdgcn_readfirstlane(tid>>6);
  const int lane = tid & 63;
  const float* __restrict__ src = (img<NBATCH) ? (x  + (size_t)img*IMG_SZ)
                                               : (xh + (size_t)(img-NBATCH)*IMG_SZ);
  float* __restrict__ dst = ((img<NBATCH) ? (out + (size_t)img*8192)
                                          : (out + (size_t)(img-NBATCH)*8192 + 4096))
                            + qq*1024;

  // ---- stage 1: T[n][b] = sum_a FY[n][a]*src[a][b]; lane owns cols 4L..4L+3 ----
  {
    const int g  = qq*4 + w;
    const int a0 = __builtin_amdgcn_readfirstlane(meta[g]);
    const int a1 = __builtin_amdgcn_readfirstlane(meta[16+g]);
    const int R  = a1 - a0;                    // rows in band (may be 0)
    const float* const srcL = src + (lane<<2); // +16B per lane

    // preamble: stage this wave's weight table fyg[g] (4 KiB) into LDS
    {
      const float4* gsrc = (const float4*)(fyg + ((size_t)g<<10));
      float4* ldst = (float4*)&SW[w][0];
      #pragma unroll
      for (int j=0;j<4;++j) ldst[lane + 64*j] = gsrc[lane + 64*j];
    }
    __syncthreads();   // weights visible; all VMEM drained -> vmcnt==0 per wave

    float acc[4][4];
    #pragma unroll
    for (int k2=0;k2<4;++k2){acc[k2][0]=0.f;acc[k2][1]=0.f;acc[k2][2]=0.f;acc[k2][3]=0.f;}

    if (R > 0){
      // ring prologue: depth 3
      gl_lds16(srcL + ((size_t)min(a0,  255)<<8), &RING[w][0][0]);
      gl_lds16(srcL + ((size_t)min(a0+1,255)<<8), &RING[w][1][0]);
      gl_lds16(srcL + ((size_t)min(a0+2,255)<<8), &RING[w][2][0]);
      #pragma unroll 1
      for (int r=0; r<R; ++r){
        // always-issue (clamped) -> exactly 4 outstanding after this issue
        gl_lds16(srcL + ((size_t)min(a0+r+3,255)<<8), &RING[w][(r+3)&3][0]);
        __builtin_amdgcn_sched_barrier(0);
        asm volatile("s_waitcnt vmcnt(3)");    // row r landed; 3 stay in flight
        __builtin_amdgcn_sched_barrier(0);
        f32x4 tv;
        lds_float* lp = (lds_float*)&RING[w][r&3][lane<<2];
        asm volatile("ds_read_b128 %0, %1" : "=&v"(tv) : "v"(lp));
        const f32x4 wv = *(const f32x4*)&SW[w][(a0+r)<<2];   // lgkm domain
        asm volatile("s_waitcnt lgkmcnt(0)");
        __builtin_amdgcn_sched_barrier(0);
        acc[0][0]=fmaf(wv.x,tv.x,acc[0][0]); acc[0][1]=fmaf(wv.x,tv.y,acc[0][1]);
        acc[0][2]=fmaf(wv.x,tv.z,acc[0][2]); acc[0][3]=fmaf(wv.x,tv.w,acc[0][3]);
        acc[1][0]=fmaf(wv.y,tv.x,acc[1][0]); acc[1][1]=fmaf(wv.y,tv.y,acc[1][1]);
        acc[1][2]=fmaf(wv.y,tv.z,acc[1][2]); acc[1][3]=fmaf(wv.y,tv.w,acc[1][3]);
        acc[2][0]=fmaf(wv.z,tv.x,acc[2][0]); acc[2][1]=fmaf(wv.z,tv.y,acc[2][1]);
        acc[2][2]=fmaf(wv.z,tv.z,acc[2][2]); acc[2][3]=fmaf(wv.z,tv.w,acc[2][3]);
        acc[3][0]=fmaf(wv.w,tv.x,acc[3][0]); acc[3][1]=fmaf(wv.w,tv.y,acc[3][1]);
        acc[3][2]=fmaf(wv.w,tv.z,acc[3][2]); acc[3][3]=fmaf(wv.w,tv.w,acc[3][3]);
      }
      asm volatile("s_waitcnt vmcnt(0)");      // per-wave drain before overlay
    }
    __syncthreads();                           // all waves' DMAs retired
    // b128 writes into Tt = TT[0..4095] (ring region), swizzle (lane ^ n)
    #pragma unroll
    for (int k2=0;k2<4;++k2){
      const int n = w*4 + k2;                  // wave-uniform row (0..15)
      float4 v; v.x=acc[k2][0]; v.y=acc[k2][1]; v.z=acc[k2][2]; v.w=acc[k2][3];
      *(float4*)&TT[(n<<8) + ((lane ^ n)<<2)] = v;
    }
  }
  __syncthreads();

  // ---- stage 2: out[n][m] = sum_b T[n][b]*FX[m][b]; lane = cc*16 + nl ----
  const int nl = lane & 15;
  const int cc = lane >> 4;
  const int q  = w*4 + cc;                     // one m-group of 4 per (wave,cc)
  const int lo4 = meta[32+q];
  const int hi  = meta[48+q];
  int ngu = (hi - lo4 + 3) >> 2;
  ngu = max(ngu, __shfl_xor(ngu,16));          // wave-uniform trip count
  ngu = max(ngu, __shfl_xor(ngu,32));          // (overrun iters: zero weights)
  const int u0  = lo4 >> 2;
  const float* wq = fxg + ((size_t)q<<10);     // [256][4] rows packed from lo4
  float o0=0.f,o1=0.f,o2=0.f,o3=0.f;
  #pragma unroll 1
  for (int it=0; it<ngu; it+=2){
    const int uA = min(u0+it,   63);
    const int uB = min(u0+it+1, 63);
    const float4 tvA = *(const float4*)&TT[(nl<<8) + ((uA ^ nl)<<2)];
    const float4 tvB = *(const float4*)&TT[(nl<<8) + ((uB ^ nl)<<2)];
    const float4 a0w = *(const float4*)(wq + it*16);
    const float4 a1w = *(const float4*)(wq + it*16 + 4);
    const float4 a2w = *(const float4*)(wq + it*16 + 8);
    const float4 a3w = *(const float4*)(wq + it*16 + 12);
    const float4 b0w = *(const float4*)(wq + it*16 + 16);
    const float4 b1w = *(const float4*)(wq + it*16 + 20);
    const float4 b2w = *(const float4*)(wq + it*16 + 24);
    const float4 b3w = *(const float4*)(wq + it*16 + 28);
    o0=fmaf(tvA.x,a0w.x,fmaf(tvA.y,a1w.x,fmaf(tvA.z,a2w.x,fmaf(tvA.w,a3w.x,o0))));
    o1=fmaf(tvA.x,a0w.y,fmaf(tvA.y,a1w.y,fmaf(tvA.z,a2w.y,fmaf(tvA.w,a3w.y,o1))));
    o2=fmaf(tvA.x,a0w.z,fmaf(tvA.y,a1w.z,fmaf(tvA.z,a2w.z,fmaf(tvA.w,a3w.z,o2))));
    o3=fmaf(tvA.x,a0w.w,fmaf(tvA.y,a1w.w,fmaf(tvA.z,a2w.w,fmaf(tvA.w,a3w.w,o3))));
    if (it+1 < ngu){
      o0=fmaf(tvB.x,b0w.x,fmaf(tvB.y,b1w.x,fmaf(tvB.z,b2w.x,fmaf(tvB.w,b3w.x,o0))));
      o1=fmaf(tvB.x,b0w.y,fmaf(tvB.y,b1w.y,fmaf(tvB.z,b2w.y,fmaf(tvB.w,b3w.y,o1))));
      o2=fmaf(tvB.x,b0w.z,fmaf(tvB.y,b1w.z,fmaf(tvB.z,b2w.z,fmaf(tvB.w,b3w.z,o2))));
      o3=fmaf(tvB.x,b0w.w,fmaf(tvB.y,b1w.w,fmaf(tvB.z,b2w.w,fmaf(tvB.w,b3w.w,o3))));
    }
  }
  __syncthreads();   // all stage-2 reads of TT done before overwrite

  // ---- transpose via LDS (stride 68 keeps float4 16B-aligned), coalesced store ----
  {
    const int m0 = q*4;
    TT[nl*68 + m0 + 0] = o0; TT[nl*68 + m0 + 1] = o1;
    TT[nl*68 + m0 + 2] = o2; TT[nl*68 + m0 + 3] = o3;
  }
  __syncthreads();
  {
    const int f = tid*4;
    const int n = f>>6, m = f&63;
    const float4 v = *(const float4*)&TT[n*68+m];
    *(float4*)(dst+f) = v;
  }
}

extern "C" void kernel_launch(void* const* d_in, const int* in_sizes, int n_in,
                              void* d_out, int out_size, void* d_ws, size_t ws_size,
                              hipStream_t stream)
{
  const float* x  = (const float*)d_in[0];
  const float* xh = (const float*)d_in[1];
  const float* h  = (const float*)d_in[2];   // only row 0 is used
  const float* Ww = (const float*)d_in[3];
  const float* Wb = (const float*)d_in[4];
  float* out = (float*)d_out;

  int*   meta = (int*)d_ws;
  float* fyg  = (float*)((char*)d_ws + 256);
  float* fxg  = (float*)((char*)d_ws + 256 + 65536);

  k_prep<<<2, 256, 0, stream>>>(h, Ww, Wb, meta, fyg, fxg);
  k_main<<<8*NBATCH, 256, 0, stream>>>(x, xh, meta, fyg, fxg, out);
}

// Round 13
// 101.733 us; speedup vs baseline: 1.0105x; 1.0105x over previous
//
#include <hip/hip_runtime.h>
#include <math.h>

#define N_FILT 64
#define IMG_DIM 256
#define IMG_SZ (256*256)
#define HDIM 1024
#define NBATCH 512

typedef __attribute__((ext_vector_type(4))) float f32x4;
typedef __attribute__((address_space(3))) float lds_float;

// ws layout (131,328 B total):
//   int meta[64]: [0..15]=loY [16..31]=hiY     (16 n-groups of 4, stage 1)
//                 [32..47]=lo4X (granule-aligned) [48..63]=hiX (16 m-groups of 4)
//   byte 256           : fyg [16][256][4] float, ABSOLUTE row index,
//                        (gamma/SY folded, zero outside band)          64 KiB
//   byte 256+65536     : fxg [16][256][4] float (1/SX folded, packed from lo4,
//                        zero-filled)                                   64 KiB

// async DMA: one wave-issue copies 64 lanes x 16B = 1KB row into LDS at
// wave-uniform base + lane*16 (gfx950 global_load_lds_dwordx4).
__device__ __forceinline__ void gl_lds16(const float* g, float* l){
  __builtin_amdgcn_global_load_lds(
      (const __attribute__((address_space(1))) unsigned int*)g,
      (__attribute__((address_space(3))) unsigned int*)l,
      16, 0, 0);
}

// grid = 2: block 0 builds the Y side (fyg), block 1 the X side (fxg).
__global__ __launch_bounds__(256) void k_prep(
    const float* __restrict__ h, const float* __restrict__ Ww,
    const float* __restrict__ Wb, int* __restrict__ meta,
    float* __restrict__ fyg, float* __restrict__ fxg)
{
  __shared__ float partial[32];      // [wave][slot]
  __shared__ float par_s[8];
  __shared__ float F[N_FILT*IMG_DIM];
  __shared__ int s_lo[64], s_hi[64], s_glo[16], s_ghi[16];
  __shared__ float ssum[4];
  const int t   = threadIdx.x;
  const int side= blockIdx.x;        // 0=Y, 1=X
  const int wv  = t>>6, ln = t&63;
  float* __restrict__ wout = side ? fxg : fyg;

  // zero-fill this side's weight buffer (packs only overwrite in-band rows)
  {
    float4 z = make_float4(0.f,0.f,0.f,0.f);
    float4* p = (float4*)wout;
    #pragma unroll
    for (int k=0;k<16;++k) p[t + 256*k] = z;
  }

  // ---- params[j] = h[0] . W_read_w[j] + W_read_b[j] (single pass over h) ----
  {
    float s0=0.f,s1=0.f,s2=0.f,s3=0.f,s4=0.f;
    for (int k=t;k<HDIM;k+=256){
      const float hv=h[k];
      s0=fmaf(hv,Ww[k        ],s0);
      s1=fmaf(hv,Ww[HDIM+k   ],s1);
      s2=fmaf(hv,Ww[2*HDIM+k ],s2);
      s3=fmaf(hv,Ww[3*HDIM+k ],s3);
      s4=fmaf(hv,Ww[4*HDIM+k ],s4);
    }
    #pragma unroll
    for (int o=32;o>0;o>>=1){
      s0+=__shfl_down(s0,o); s1+=__shfl_down(s1,o); s2+=__shfl_down(s2,o);
      s3+=__shfl_down(s3,o); s4+=__shfl_down(s4,o);
    }
    if (ln==0){ partial[wv*8+0]=s0; partial[wv*8+1]=s1; partial[wv*8+2]=s2;
                partial[wv*8+3]=s3; partial[wv*8+4]=s4; }
  }
  __syncthreads();
  if (t<5) par_s[t]=partial[t]+partial[8+t]+partial[16+t]+partial[24+t]+Wb[t];
  __syncthreads();

  const float var   = expf(par_s[2]+1e-8f);
  const float dt    = expf(par_s[3]);
  const float gamma = expf(par_s[4]);
  const float gC = 0.5f*257.f*(par_s[side?0:1]+1.f);  // Y<-par[1], X<-par[0]
  const float d  = dt*(255.f/63.f);
  const float sub= -32.5f*d;
  const float inv2v = 1.f/(2.f*var);
  const float w88v  = 88.f*var;   // band cutoff: e(a)/e(peak) >= exp(-44)

  if (t<64){
    float mu = gC + sub + d*(float)t;
    float astar = fminf(255.f, fmaxf(0.f, rintf(mu)));   // clamped peak
    float t0 = (astar-mu)*(astar-mu);
    float r  = sqrtf(t0 + w88v);
    int lo = (int)ceilf(mu-r); int hi = (int)floorf(mu+r)+1;
    lo = lo<0?0:lo; hi = hi>256?256:hi; if (hi<lo) hi=lo;
    s_lo[t]=lo; s_hi[t]=hi;
  }
  __syncthreads();
  if (t<16){
    int lo=256, hi=0;
    #pragma unroll
    for (int k2=0;k2<4;++k2){ lo=min(lo,s_lo[t*4+k2]); hi=max(hi,s_hi[t*4+k2]); }
    if (hi<lo){lo=0;hi=0;}
    if (side==0){ meta[t]=lo; meta[16+t]=hi; }
    else        { lo &= ~3;  meta[32+t]=lo; meta[48+t]=hi; }  // granule-aligned
    s_glo[t]=lo; s_ghi[t]=hi;
  }
  // F + global sum
  float sum=0.f;
  #pragma unroll
  for (int k=0;k<64;++k){
    int idx=t+256*k;
    int n=idx>>8, a=idx&255;
    float mu = gC+sub+d*(float)n;
    float dx=(float)a-mu;
    float e=expf(-dx*dx*inv2v);
    F[idx]=e; sum+=e;
  }
  #pragma unroll
  for (int o=32;o>0;o>>=1) sum+=__shfl_down(sum,o);
  if (ln==0) ssum[wv]=sum;
  __syncthreads();
  const float stot = ssum[0]+ssum[1]+ssum[2]+ssum[3];
  const float sc = (side==0 ? gamma : 1.f)/stot;   // fold gamma into Y side
  #pragma unroll
  for (int k=0;k<64;++k){
    int idx=t+256*k;
    int n=idx>>8, a=idx&255, g=n>>2;
    int lo=s_glo[g], hi=s_ghi[g];
    if (a>=lo && a<hi){
      // Y side: ABSOLUTE row index (ring kernel); X side: packed from lo4
      const int row = side ? (a-lo) : a;
      wout[(size_t)((g<<10)+(row<<2)+(n&3))] = F[idx]*sc;
    }
  }
}

// 4096 blocks: 4 blocks per image (16 filters each). 4 waves; wave w owns
// stage-1 n-group g=qq*4+w and stage-2 m-group q=w*4+(lane>>4).
// Stage 1: wave-private ring of 4 chunk-slots x 2 rows, depth-3-chunk
// lookahead (6 rows / 6KB per wave in flight), constant clobber-free
// s_waitcnt vmcnt(6). Zero non-DMA VMEM in the loop (weights pre-staged
// in LDS, PADDED to 257 rows: row 256 = 0 so the odd-R clamped tail row
// is a bitwise no-op — fixes round-12's OOB weight read). Rule-18 consume.
__global__ __launch_bounds__(256, 3) void k_main(
    const float* __restrict__ x, const float* __restrict__ xh,
    const int* __restrict__ meta, const float* __restrict__ fyg,
    const float* __restrict__ fxg, float* __restrict__ out)
{
  __shared__ float RING[4][4][512];  // [wave][slot][2 rows x 256] = 32 KiB
  __shared__ float SW[4][1028];      // [wave][257 rows x 4], row 256 = zeros
  float* const TT = &RING[0][0][0];  // Tt[16][256] overlays the ring later
  const int bid = blockIdx.x;
  const int lg  = ((bid&7)<<9) | (bid>>3);   // same-image quads -> same XCD
  const int img = lg>>2, qq = lg&3;
  const int tid = threadIdx.x;
  const int w    = __builtin_amdgcn_readfirstlane(tid>>6);
  const int lane = tid & 63;
  const float* __restrict__ src = (img<NBATCH) ? (x  + (size_t)img*IMG_SZ)
                                               : (xh + (size_t)(img-NBATCH)*IMG_SZ);
  float* __restrict__ dst = ((img<NBATCH) ? (out + (size_t)img*8192)
                                          : (out + (size_t)(img-NBATCH)*8192 + 4096))
                            + qq*1024;

  // ---- stage 1: T[n][b] = sum_a FY[n][a]*src[a][b]; lane owns cols 4L..4L+3 ----
  {
    const int g  = qq*4 + w;
    const int a0 = __builtin_amdgcn_readfirstlane(meta[g]);
    const int a1 = __builtin_amdgcn_readfirstlane(meta[16+g]);
    const int R  = a1 - a0;                    // rows in band (may be 0)
    const int CC = (R + 1) >> 1;               // 2-row chunks
    const float* const srcL = src + (lane<<2); // +16B per lane

    // preamble: stage this wave's weight table fyg[g] (4 KiB) into LDS,
    // then zero the pad row (absolute row 256).
    {
      const float4* gsrc = (const float4*)(fyg + ((size_t)g<<10));
      float4* ldst = (float4*)&SW[w][0];
      #pragma unroll
      for (int j=0;j<4;++j) ldst[lane + 64*j] = gsrc[lane + 64*j];
      if (lane < 4) SW[w][1024 + lane] = 0.f;
    }
    __syncthreads();   // weights visible; all VMEM drained -> vmcnt==0 per wave

    float acc[4][4];
    #pragma unroll
    for (int k2=0;k2<4;++k2){acc[k2][0]=0.f;acc[k2][1]=0.f;acc[k2][2]=0.f;acc[k2][3]=0.f;}

#define DMA2(ch) do{ const int _c=(ch); const int _r0=a0+2*_c; \
    float* const _b = &RING[w][_c&3][0]; \
    gl_lds16(srcL + ((size_t)min(_r0,  255)<<8), _b); \
    gl_lds16(srcL + ((size_t)min(_r0+1,255)<<8), _b + 256); }while(0)

    if (R > 0){
      // ring prologue: 3 chunks (6 rows, 6 DMAs) in flight
      DMA2(0); DMA2(1); DMA2(2);
      #pragma unroll 1
      for (int c=0; c<CC; ++c){
        // always-issue (clamped) -> 8 outstanding after this issue
        DMA2(c+3);
        __builtin_amdgcn_sched_barrier(0);
        asm volatile("s_waitcnt vmcnt(6)");    // chunk c landed; 3 chunks in flight
        __builtin_amdgcn_sched_barrier(0);
        f32x4 t0, t1;
        lds_float* lp0 = (lds_float*)&RING[w][c&3][lane<<2];
        lds_float* lp1 = (lds_float*)&RING[w][c&3][256 + (lane<<2)];
        asm volatile("ds_read_b128 %0, %1" : "=&v"(t0) : "v"(lp0));
        asm volatile("ds_read_b128 %0, %1" : "=&v"(t1) : "v"(lp1));
        // row0 index <= a1-1 <= 255; row1 index <= a1 <= 256 -> pad row (zeros)
        const f32x4 w0 = *(const f32x4*)&SW[w][(a0+2*c  )<<2];   // lgkm domain
        const f32x4 w1 = *(const f32x4*)&SW[w][(a0+2*c+1)<<2];
        asm volatile("s_waitcnt lgkmcnt(0)");
        __builtin_amdgcn_sched_barrier(0);
        acc[0][0]=fmaf(w0.x,t0.x,acc[0][0]); acc[0][1]=fmaf(w0.x,t0.y,acc[0][1]);
        acc[0][2]=fmaf(w0.x,t0.z,acc[0][2]); acc[0][3]=fmaf(w0.x,t0.w,acc[0][3]);
        acc[1][0]=fmaf(w0.y,t0.x,acc[1][0]); acc[1][1]=fmaf(w0.y,t0.y,acc[1][1]);
        acc[1][2]=fmaf(w0.y,t0.z,acc[1][2]); acc[1][3]=fmaf(w0.y,t0.w,acc[1][3]);
        acc[2][0]=fmaf(w0.z,t0.x,acc[2][0]); acc[2][1]=fmaf(w0.z,t0.y,acc[2][1]);
        acc[2][2]=fmaf(w0.z,t0.z,acc[2][2]); acc[2][3]=fmaf(w0.z,t0.w,acc[2][3]);
        acc[3][0]=fmaf(w0.w,t0.x,acc[3][0]); acc[3][1]=fmaf(w0.w,t0.y,acc[3][1]);
        acc[3][2]=fmaf(w0.w,t0.z,acc[3][2]); acc[3][3]=fmaf(w0.w,t0.w,acc[3][3]);
        acc[0][0]=fmaf(w1.x,t1.x,acc[0][0]); acc[0][1]=fmaf(w1.x,t1.y,acc[0][1]);
        acc[0][2]=fmaf(w1.x,t1.z,acc[0][2]); acc[0][3]=fmaf(w1.x,t1.w,acc[0][3]);
        acc[1][0]=fmaf(w1.y,t1.x,acc[1][0]); acc[1][1]=fmaf(w1.y,t1.y,acc[1][1]);
        acc[1][2]=fmaf(w1.y,t1.z,acc[1][2]); acc[1][3]=fmaf(w1.y,t1.w,acc[1][3]);
        acc[2][0]=fmaf(w1.z,t1.x,acc[2][0]); acc[2][1]=fmaf(w1.z,t1.y,acc[2][1]);
        acc[2][2]=fmaf(w1.z,t1.z,acc[2][2]); acc[2][3]=fmaf(w1.z,t1.w,acc[2][3]);
        acc[3][0]=fmaf(w1.w,t1.x,acc[3][0]); acc[3][1]=fmaf(w1.w,t1.y,acc[3][1]);
        acc[3][2]=fmaf(w1.w,t1.z,acc[3][2]); acc[3][3]=fmaf(w1.w,t1.w,acc[3][3]);
      }
      asm volatile("s_waitcnt vmcnt(0)");      // per-wave drain before overlay
    }
#undef DMA2
    __syncthreads();                           // all waves' DMAs retired
    // b128 writes into Tt = TT[0..4095] (ring region), swizzle (lane ^ n)
    #pragma unroll
    for (int k2=0;k2<4;++k2){
      const int n = w*4 + k2;                  // wave-uniform row (0..15)
      float4 v; v.x=acc[k2][0]; v.y=acc[k2][1]; v.z=acc[k2][2]; v.w=acc[k2][3];
      *(float4*)&TT[(n<<8) + ((lane ^ n)<<2)] = v;
    }
  }
  __syncthreads();

  // ---- stage 2: out[n][m] = sum_b T[n][b]*FX[m][b]; lane = cc*16 + nl ----
  const int nl = lane & 15;
  const int cc = lane >> 4;
  const int q  = w*4 + cc;                     // one m-group of 4 per (wave,cc)
  const int lo4 = meta[32+q];
  const int hi  = meta[48+q];
  int ngu = (hi - lo4 + 3) >> 2;
  ngu = max(ngu, __shfl_xor(ngu,16));          // wave-uniform trip count
  ngu = max(ngu, __shfl_xor(ngu,32));          // (overrun iters: zero weights)
  const int u0  = lo4 >> 2;
  const float* wq = fxg + ((size_t)q<<10);     // [256][4] rows packed from lo4
  float o0=0.f,o1=0.f,o2=0.f,o3=0.f;
  #pragma unroll 1
  for (int it=0; it<ngu; it+=2){
    const int uA = min(u0+it,   63);
    const int uB = min(u0+it+1, 63);
    const float4 tvA = *(const float4*)&TT[(nl<<8) + ((uA ^ nl)<<2)];
    const float4 tvB = *(const float4*)&TT[(nl<<8) + ((uB ^ nl)<<2)];
    const float4 a0w = *(const float4*)(wq + it*16);
    const float4 a1w = *(const float4*)(wq + it*16 + 4);
    const float4 a2w = *(const float4*)(wq + it*16 + 8);
    const float4 a3w = *(const float4*)(wq + it*16 + 12);
    const float4 b0w = *(const float4*)(wq + it*16 + 16);
    const float4 b1w = *(const float4*)(wq + it*16 + 20);
    const float4 b2w = *(const float4*)(wq + it*16 + 24);
    const float4 b3w = *(const float4*)(wq + it*16 + 28);
    o0=fmaf(tvA.x,a0w.x,fmaf(tvA.y,a1w.x,fmaf(tvA.z,a2w.x,fmaf(tvA.w,a3w.x,o0))));
    o1=fmaf(tvA.x,a0w.y,fmaf(tvA.y,a1w.y,fmaf(tvA.z,a2w.y,fmaf(tvA.w,a3w.y,o1))));
    o2=fmaf(tvA.x,a0w.z,fmaf(tvA.y,a1w.z,fmaf(tvA.z,a2w.z,fmaf(tvA.w,a3w.z,o2))));
    o3=fmaf(tvA.x,a0w.w,fmaf(tvA.y,a1w.w,fmaf(tvA.z,a2w.w,fmaf(tvA.w,a3w.w,o3))));
    if (it+1 < ngu){
      o0=fmaf(tvB.x,b0w.x,fmaf(tvB.y,b1w.x,fmaf(tvB.z,b2w.x,fmaf(tvB.w,b3w.x,o0))));
      o1=fmaf(tvB.x,b0w.y,fmaf(tvB.y,b1w.y,fmaf(tvB.z,b2w.y,fmaf(tvB.w,b3w.y,o1))));
      o2=fmaf(tvB.x,b0w.z,fmaf(tvB.y,b1w.z,fmaf(tvB.z,b2w.z,fmaf(tvB.w,b3w.z,o2))));
      o3=fmaf(tvB.x,b0w.w,fmaf(tvB.y,b1w.w,fmaf(tvB.z,b2w.w,fmaf(tvB.w,b3w.w,o3))));
    }
  }
  __syncthreads();   // all stage-2 reads of TT done before overwrite

  // ---- transpose via LDS (stride 68 keeps float4 16B-aligned), coalesced store ----
  {
    const int m0 = q*4;
    TT[nl*68 + m0 + 0] = o0; TT[nl*68 + m0 + 1] = o1;
    TT[nl*68 + m0 + 2] = o2; TT[nl*68 + m0 + 3] = o3;
  }
  __syncthreads();
  {
    const int f = tid*4;
    const int n = f>>6, m = f&63;
    const float4 v = *(const float4*)&TT[n*68+m];
    *(float4*)(dst+f) = v;
  }
}

extern "C" void kernel_launch(void* const* d_in, const int* in_sizes, int n_in,
                              void* d_out, int out_size, void* d_ws, size_t ws_size,
                              hipStream_t stream)
{
  const float* x  = (const float*)d_in[0];
  const float* xh = (const float*)d_in[1];
  const float* h  = (const float*)d_in[2];   // only row 0 is used
  const float* Ww = (const float*)d_in[3];
  const float* Wb = (const float*)d_in[4];
  float* out = (float*)d_out;

  int*   meta = (int*)d_ws;
  float* fyg  = (float*)((char*)d_ws + 256);
  float* fxg  = (float*)((char*)d_ws + 256 + 65536);

  k_prep<<<2, 256, 0, stream>>>(h, Ww, Wb, meta, fyg, fxg);
  k_main<<<8*NBATCH, 256, 0, stream>>>(x, xh, meta, fyg, fxg, out);
}

// Round 14
// 92.250 us; speedup vs baseline: 1.1144x; 1.1028x over previous
//
#include <hip/hip_runtime.h>
#include <math.h>

#define N_FILT 64
#define IMG_DIM 256
#define IMG_SZ (256*256)
#define HDIM 1024
#define NBATCH 512

typedef __attribute__((ext_vector_type(4))) float f32x4;
typedef __attribute__((address_space(3))) float lds_float;

// ws layout (131,328 B total):
//   int meta[64]: [0..15]=loY [16..31]=hiY     (16 n-groups of 4, stage 1)
//                 [32..47]=lo4X (granule-aligned) [48..63]=hiX (16 m-groups of 4)
//   byte 256           : fyg [16][256][4] float (gamma/SY folded, packed from lo,
//                        zero-filled beyond band)                      64 KiB
//   byte 256+65536     : fxg [16][256][4] float (1/SX folded, packed from lo4,
//                        zero-filled)                                   64 KiB

// async DMA: one wave-issue copies 64 lanes x 16B = 1KB row into LDS at
// wave-uniform base + lane*16 (gfx950 global_load_lds_dwordx4).
__device__ __forceinline__ void gl_lds16(const float* g, float* l){
  __builtin_amdgcn_global_load_lds(
      (const __attribute__((address_space(1))) unsigned int*)g,
      (__attribute__((address_space(3))) unsigned int*)l,
      16, 0, 0);
}

// grid = 2: block 0 builds the Y side (fyg), block 1 the X side (fxg).
// EXACT round-8 version (relative packing on both sides).
__global__ __launch_bounds__(256) void k_prep(
    const float* __restrict__ h, const float* __restrict__ Ww,
    const float* __restrict__ Wb, int* __restrict__ meta,
    float* __restrict__ fyg, float* __restrict__ fxg)
{
  __shared__ float partial[32];      // [wave][slot]
  __shared__ float par_s[8];
  __shared__ float F[N_FILT*IMG_DIM];
  __shared__ int s_lo[64], s_hi[64], s_glo[16], s_ghi[16];
  __shared__ float ssum[4];
  const int t   = threadIdx.x;
  const int side= blockIdx.x;        // 0=Y, 1=X
  const int wv  = t>>6, ln = t&63;
  float* __restrict__ wout = side ? fxg : fyg;

  // zero-fill this side's weight buffer (packs only overwrite in-band rows)
  {
    float4 z = make_float4(0.f,0.f,0.f,0.f);
    float4* p = (float4*)wout;
    #pragma unroll
    for (int k=0;k<16;++k) p[t + 256*k] = z;
  }

  // ---- params[j] = h[0] . W_read_w[j] + W_read_b[j] (single pass over h) ----
  {
    float s0=0.f,s1=0.f,s2=0.f,s3=0.f,s4=0.f;
    for (int k=t;k<HDIM;k+=256){
      const float hv=h[k];
      s0=fmaf(hv,Ww[k        ],s0);
      s1=fmaf(hv,Ww[HDIM+k   ],s1);
      s2=fmaf(hv,Ww[2*HDIM+k ],s2);
      s3=fmaf(hv,Ww[3*HDIM+k ],s3);
      s4=fmaf(hv,Ww[4*HDIM+k ],s4);
    }
    #pragma unroll
    for (int o=32;o>0;o>>=1){
      s0+=__shfl_down(s0,o); s1+=__shfl_down(s1,o); s2+=__shfl_down(s2,o);
      s3+=__shfl_down(s3,o); s4+=__shfl_down(s4,o);
    }
    if (ln==0){ partial[wv*8+0]=s0; partial[wv*8+1]=s1; partial[wv*8+2]=s2;
                partial[wv*8+3]=s3; partial[wv*8+4]=s4; }
  }
  __syncthreads();
  if (t<5) par_s[t]=partial[t]+partial[8+t]+partial[16+t]+partial[24+t]+Wb[t];
  __syncthreads();

  const float var   = expf(par_s[2]+1e-8f);
  const float dt    = expf(par_s[3]);
  const float gamma = expf(par_s[4]);
  const float gC = 0.5f*257.f*(par_s[side?0:1]+1.f);  // Y<-par[1], X<-par[0]
  const float d  = dt*(255.f/63.f);
  const float sub= -32.5f*d;
  const float inv2v = 1.f/(2.f*var);
  const float w88v  = 88.f*var;   // band cutoff: e(a)/e(peak) >= exp(-44)

  if (t<64){
    float mu = gC + sub + d*(float)t;
    float astar = fminf(255.f, fmaxf(0.f, rintf(mu)));   // clamped peak
    float t0 = (astar-mu)*(astar-mu);
    float r  = sqrtf(t0 + w88v);
    int lo = (int)ceilf(mu-r); int hi = (int)floorf(mu+r)+1;
    lo = lo<0?0:lo; hi = hi>256?256:hi; if (hi<lo) hi=lo;
    s_lo[t]=lo; s_hi[t]=hi;
  }
  __syncthreads();
  if (t<16){
    int lo=256, hi=0;
    #pragma unroll
    for (int k2=0;k2<4;++k2){ lo=min(lo,s_lo[t*4+k2]); hi=max(hi,s_hi[t*4+k2]); }
    if (hi<lo){lo=0;hi=0;}
    if (side==0){ meta[t]=lo; meta[16+t]=hi; }
    else        { lo &= ~3;  meta[32+t]=lo; meta[48+t]=hi; }  // granule-aligned
    s_glo[t]=lo; s_ghi[t]=hi;
  }
  // F + global sum
  float sum=0.f;
  #pragma unroll
  for (int k=0;k<64;++k){
    int idx=t+256*k;
    int n=idx>>8, a=idx&255;
    float mu = gC+sub+d*(float)n;
    float dx=(float)a-mu;
    float e=expf(-dx*dx*inv2v);
    F[idx]=e; sum+=e;
  }
  #pragma unroll
  for (int o=32;o>0;o>>=1) sum+=__shfl_down(sum,o);
  if (ln==0) ssum[wv]=sum;
  __syncthreads();
  const float stot = ssum[0]+ssum[1]+ssum[2]+ssum[3];
  const float sc = (side==0 ? gamma : 1.f)/stot;   // fold gamma into Y side
  #pragma unroll
  for (int k=0;k<64;++k){
    int idx=t+256*k;
    int n=idx>>8, a=idx&255, g=n>>2;
    int lo=s_glo[g], hi=s_ghi[g];
    if (a>=lo && a<hi) wout[(size_t)((g<<10)+((a-lo)<<2)+(n&3))] = F[idx]*sc;
  }
}

// 2048 blocks: each owns an (x, x_hat) IMAGE PAIR p and quad qq (16 filters).
// 4 waves; wave w owns stage-1 n-group g=qq*4+w (both images) and stage-2
// m-group q=w*4+(lane>>4) (both images).
// Stage 1 = round-8 ring machinery doubled: 4 chunk-slots x (2 rows x 2 imgs),
// depth-3-chunk lookahead (12 DMAs / 12 KB per wave in flight), constant
// clobber-free s_waitcnt vmcnt(12), asm ds_read consume (rule-18 recipe).
// Halves block generations (16->8 per CU) and amortizes all fixed costs x2.
__global__ __launch_bounds__(256, 2) void k_main(
    const float* __restrict__ x, const float* __restrict__ xh,
    const int* __restrict__ meta, const float* __restrict__ fyg,
    const float* __restrict__ fxg, float* __restrict__ out)
{
  __shared__ float POOL[16384];   // 64 KiB
  // stage1 ring: POOL[w*4096 + slot*1024 + {0:A0, 256:B0, 512:A1, 768:B1}]
  // overlay:     TT_A = POOL[0..4095], TT_B = POOL[4096..8191]
  //              TRA  = POOL[8192..9279], TRB = POOL[9472..10559]
  const int bid = blockIdx.x;
  const int lg  = ((bid&7)<<8) | (bid>>3);   // 2048 blocks, bijective
  const int p   = lg>>2, qq = lg&3;
  const int tid = threadIdx.x;
  const int w    = __builtin_amdgcn_readfirstlane(tid>>6);
  const int lane = tid & 63;
  const float* __restrict__ srcA = x  + (size_t)p*IMG_SZ;
  const float* __restrict__ srcB = xh + (size_t)p*IMG_SZ;
  float* __restrict__ dstA = out + (size_t)p*8192 + qq*1024;
  float* __restrict__ dstB = dstA + 4096;

  float accA[4][4], accB[4][4];
  // ---- stage 1: T[n][b] = sum_a FY[n][a]*src[a][b] for BOTH images ----
  {
    const int g  = qq*4 + w;
    const int a0 = __builtin_amdgcn_readfirstlane(meta[g]);
    const int a1 = __builtin_amdgcn_readfirstlane(meta[16+g]);
    const int R  = a1 - a0;                    // rows in band (may be 0)
    const int CC = (R + 1) >> 1;               // 2-row chunks
    const float* const wp = fyg + ((size_t)g<<10);   // [256][4] rel., zero-padded
    const float* const sA = srcA + (lane<<2);
    const float* const sB = srcB + (lane<<2);
    #pragma unroll
    for (int k2=0;k2<4;++k2){
      accA[k2][0]=0.f;accA[k2][1]=0.f;accA[k2][2]=0.f;accA[k2][3]=0.f;
      accB[k2][0]=0.f;accB[k2][1]=0.f;accB[k2][2]=0.f;accB[k2][3]=0.f;
    }

#define DMA4(ch) do{ const int _c=(ch); const int _r0=a0+2*_c; \
    float* const _b = &POOL[(w<<12) + ((_c&3)<<10)]; \
    gl_lds16(sA + ((size_t)min(_r0,  255)<<8), _b); \
    gl_lds16(sB + ((size_t)min(_r0,  255)<<8), _b+256); \
    gl_lds16(sA + ((size_t)min(_r0+1,255)<<8), _b+512); \
    gl_lds16(sB + ((size_t)min(_r0+1,255)<<8), _b+768); }while(0)
#define FMAROW(ACC,W,T) do{ \
    ACC[0][0]=fmaf(W.x,T.x,ACC[0][0]); ACC[0][1]=fmaf(W.x,T.y,ACC[0][1]); \
    ACC[0][2]=fmaf(W.x,T.z,ACC[0][2]); ACC[0][3]=fmaf(W.x,T.w,ACC[0][3]); \
    ACC[1][0]=fmaf(W.y,T.x,ACC[1][0]); ACC[1][1]=fmaf(W.y,T.y,ACC[1][1]); \
    ACC[1][2]=fmaf(W.y,T.z,ACC[1][2]); ACC[1][3]=fmaf(W.y,T.w,ACC[1][3]); \
    ACC[2][0]=fmaf(W.z,T.x,ACC[2][0]); ACC[2][1]=fmaf(W.z,T.y,ACC[2][1]); \
    ACC[2][2]=fmaf(W.z,T.z,ACC[2][2]); ACC[2][3]=fmaf(W.z,T.w,ACC[2][3]); \
    ACC[3][0]=fmaf(W.w,T.x,ACC[3][0]); ACC[3][1]=fmaf(W.w,T.y,ACC[3][1]); \
    ACC[3][2]=fmaf(W.w,T.z,ACC[3][2]); ACC[3][3]=fmaf(W.w,T.w,ACC[3][3]); }while(0)

    if (R > 0){
      // ring prologue: 3 chunks (12 DMAs, 12 KB) in flight
      DMA4(0); DMA4(1); DMA4(2);
      #pragma unroll 1
      for (int c=0; c<CC; ++c){
        DMA4(c+3);                             // 16 outstanding after issue
        __builtin_amdgcn_sched_barrier(0);
        asm volatile("s_waitcnt vmcnt(12)");   // chunk c landed; 3 in flight
        __builtin_amdgcn_sched_barrier(0);
        f32x4 tA0,tB0,tA1,tB1;
        lds_float* l0 = (lds_float*)&POOL[(w<<12) + ((c&3)<<10) + (lane<<2)];
        asm volatile("ds_read_b128 %0, %1"             : "=&v"(tA0) : "v"(l0));
        asm volatile("ds_read_b128 %0, %1 offset:1024" : "=&v"(tB0) : "v"(l0));
        asm volatile("ds_read_b128 %0, %1 offset:2048" : "=&v"(tA1) : "v"(l0));
        asm volatile("ds_read_b128 %0, %1 offset:3072" : "=&v"(tB1) : "v"(l0));
        // relative rows: 2c <= 255; 2c+1 <= R <= 256 -> clamp; zero-fill beyond band
        const f32x4 w0 = ((const f32x4*)wp)[min(2*c,  255)];   // uniform s_load
        const f32x4 w1 = ((const f32x4*)wp)[min(2*c+1,255)];
        asm volatile("s_waitcnt lgkmcnt(0)");
        __builtin_amdgcn_sched_barrier(0);
        FMAROW(accA,w0,tA0); FMAROW(accB,w0,tB0);
        FMAROW(accA,w1,tA1); FMAROW(accB,w1,tB1);
      }
      asm volatile("s_waitcnt vmcnt(0)");      // per-wave drain before overlay
    }
#undef DMA4
  }
  __syncthreads();                             // all waves' DMAs retired
  // b128 writes into TT_A / TT_B, granule-XOR swizzle (lane ^ n)
  #pragma unroll
  for (int k2=0;k2<4;++k2){
    const int n = w*4 + k2;                    // wave-uniform row (0..15)
    float4 va; va.x=accA[k2][0]; va.y=accA[k2][1]; va.z=accA[k2][2]; va.w=accA[k2][3];
    float4 vb; vb.x=accB[k2][0]; vb.y=accB[k2][1]; vb.z=accB[k2][2]; vb.w=accB[k2][3];
    *(float4*)&POOL[       (n<<8) + ((lane ^ n)<<2)] = va;
    *(float4*)&POOL[4096 + (n<<8) + ((lane ^ n)<<2)] = vb;
  }
  __syncthreads();

  // ---- stage 2: out[n][m] = sum_b T[n][b]*FX[m][b]; lane = cc*16 + nl ----
  const int nl = lane & 15;
  const int cc = lane >> 4;
  const int q  = w*4 + cc;                     // one m-group of 4 per (wave,cc)
  const int lo4 = meta[32+q];
  const int hi  = meta[48+q];
  int ngu = (hi - lo4 + 3) >> 2;
  ngu = max(ngu, __shfl_xor(ngu,16));          // wave-uniform trip count
  ngu = max(ngu, __shfl_xor(ngu,32));          // (overrun iters: zero weights)
  const int u0  = lo4 >> 2;
  const float* wq = fxg + ((size_t)q<<10);     // [256][4] rows packed from lo4
  float oA0=0.f,oA1=0.f,oA2=0.f,oA3=0.f;
  float oB0=0.f,oB1=0.f,oB2=0.f,oB3=0.f;
  #pragma unroll 2
  for (int it=0; it<ngu; it+=2){
    const int uA_ = min(u0+it,   63);
    const int uB_ = min(u0+it+1, 63);
    const float4 tA0 = *(const float4*)&POOL[       (nl<<8) + ((uA_^nl)<<2)];
    const float4 tA1 = *(const float4*)&POOL[       (nl<<8) + ((uB_^nl)<<2)];
    const float4 tB0 = *(const float4*)&POOL[4096 + (nl<<8) + ((uA_^nl)<<2)];
    const float4 tB1 = *(const float4*)&POOL[4096 + (nl<<8) + ((uB_^nl)<<2)];
    const float4 a0w = *(const float4*)(wq + it*16);      // shared by A and B
    const float4 a1w = *(const float4*)(wq + it*16 + 4);
    const float4 a2w = *(const float4*)(wq + it*16 + 8);
    const float4 a3w = *(const float4*)(wq + it*16 + 12);
    const float4 b0w = *(const float4*)(wq + it*16 + 16);
    const float4 b1w = *(const float4*)(wq + it*16 + 20);
    const float4 b2w = *(const float4*)(wq + it*16 + 24);
    const float4 b3w = *(const float4*)(wq + it*16 + 28);
    oA0=fmaf(tA0.x,a0w.x,fmaf(tA0.y,a1w.x,fmaf(tA0.z,a2w.x,fmaf(tA0.w,a3w.x,oA0))));
    oA1=fmaf(tA0.x,a0w.y,fmaf(tA0.y,a1w.y,fmaf(tA0.z,a2w.y,fmaf(tA0.w,a3w.y,oA1))));
    oA2=fmaf(tA0.x,a0w.z,fmaf(tA0.y,a1w.z,fmaf(tA0.z,a2w.z,fmaf(tA0.w,a3w.z,oA2))));
    oA3=fmaf(tA0.x,a0w.w,fmaf(tA0.y,a1w.w,fmaf(tA0.z,a2w.w,fmaf(tA0.w,a3w.w,oA3))));
    oB0=fmaf(tB0.x,a0w.x,fmaf(tB0.y,a1w.x,fmaf(tB0.z,a2w.x,fmaf(tB0.w,a3w.x,oB0))));
    oB1=fmaf(tB0.x,a0w.y,fmaf(tB0.y,a1w.y,fmaf(tB0.z,a2w.y,fmaf(tB0.w,a3w.y,oB1))));
    oB2=fmaf(tB0.x,a0w.z,fmaf(tB0.y,a1w.z,fmaf(tB0.z,a2w.z,fmaf(tB0.w,a3w.z,oB2))));
    oB3=fmaf(tB0.x,a0w.w,fmaf(tB0.y,a1w.w,fmaf(tB0.z,a2w.w,fmaf(tB0.w,a3w.w,oB3))));
    if (it+1 < ngu){
      oA0=fmaf(tA1.x,b0w.x,fmaf(tA1.y,b1w.x,fmaf(tA1.z,b2w.x,fmaf(tA1.w,b3w.x,oA0))));
      oA1=fmaf(tA1.x,b0w.y,fmaf(tA1.y,b1w.y,fmaf(tA1.z,b2w.y,fmaf(tA1.w,b3w.y,oA1))));
      oA2=fmaf(tA1.x,b0w.z,fmaf(tA1.y,b1w.z,fmaf(tA1.z,b2w.z,fmaf(tA1.w,b3w.z,oA2))));
      oA3=fmaf(tA1.x,b0w.w,fmaf(tA1.y,b1w.w,fmaf(tA1.z,b2w.w,fmaf(tA1.w,b3w.w,oA3))));
      oB0=fmaf(tB1.x,b0w.x,fmaf(tB1.y,b1w.x,fmaf(tB1.z,b2w.x,fmaf(tB1.w,b3w.x,oB0))));
      oB1=fmaf(tB1.x,b0w.y,fmaf(tB1.y,b1w.y,fmaf(tB1.z,b2w.y,fmaf(tB1.w,b3w.y,oB1))));
      oB2=fmaf(tB1.x,b0w.z,fmaf(tB1.y,b1w.z,fmaf(tB1.z,b2w.z,fmaf(tB1.w,b3w.z,oB2))));
      oB3=fmaf(tB1.x,b0w.w,fmaf(tB1.y,b1w.w,fmaf(tB1.z,b2w.w,fmaf(tB1.w,b3w.w,oB3))));
    }
  }
  // transpose bufs live at POOL[8192..] (dead ring space) — disjoint from TT,
  // so no barrier needed between stage-2 TT reads and these writes.
  {
    const int m0 = q*4;
    POOL[8192 + nl*68 + m0 + 0] = oA0; POOL[8192 + nl*68 + m0 + 1] = oA1;
    POOL[8192 + nl*68 + m0 + 2] = oA2; POOL[8192 + nl*68 + m0 + 3] = oA3;
    POOL[9472 + nl*68 + m0 + 0] = oB0; POOL[9472 + nl*68 + m0 + 1] = oB1;
    POOL[9472 + nl*68 + m0 + 2] = oB2; POOL[9472 + nl*68 + m0 + 3] = oB3;
  }
  __syncthreads();
  {
    const int f = tid*4;
    const int n = f>>6, m = f&63;
    *(float4*)(dstA+f) = *(const float4*)&POOL[8192 + n*68 + m];
    *(float4*)(dstB+f) = *(const float4*)&POOL[9472 + n*68 + m];
  }
#undef FMAROW
}

extern "C" void kernel_launch(void* const* d_in, const int* in_sizes, int n_in,
                              void* d_out, int out_size, void* d_ws, size_t ws_size,
                              hipStream_t stream)
{
  const float* x  = (const float*)d_in[0];
  const float* xh = (const float*)d_in[1];
  const float* h  = (const float*)d_in[2];   // only row 0 is used
  const float* Ww = (const float*)d_in[3];
  const float* Wb = (const float*)d_in[4];
  float* out = (float*)d_out;

  int*   meta = (int*)d_ws;
  float* fyg  = (float*)((char*)d_ws + 256);
  float* fxg  = (float*)((char*)d_ws + 256 + 65536);

  k_prep<<<2, 256, 0, stream>>>(h, Ww, Wb, meta, fyg, fxg);
  k_main<<<4*NBATCH, 256, 0, stream>>>(x, xh, meta, fyg, fxg, out);
}

// Round 15
// 85.711 us; speedup vs baseline: 1.1995x; 1.0763x over previous
//
#include <hip/hip_runtime.h>
#include <math.h>

#define N_FILT 64
#define IMG_DIM 256
#define IMG_SZ (256*256)
#define HDIM 1024
#define NBATCH 512

typedef __attribute__((ext_vector_type(4))) float f32x4;
typedef __attribute__((address_space(3))) float lds_float;

// ws layout (131,328 B total):
//   int meta[64]: [0..15]=loY [16..31]=hiY     (16 n-groups of 4, stage 1)
//                 [32..47]=lo4X (granule-aligned) [48..63]=hiX (16 m-groups of 4)
//   byte 256           : fyg [16][256][4] float (gamma/SY folded, packed from lo,
//                        zero-filled beyond band)                      64 KiB
//   byte 256+65536     : fxg [16][256][4] float (1/SX folded, packed from lo4,
//                        zero-filled)                                   64 KiB

// async DMA: one wave-issue copies 64 lanes x 16B = 1KB row into LDS at
// wave-uniform base + lane*16 (gfx950 global_load_lds_dwordx4).
__device__ __forceinline__ void gl_lds16(const float* g, float* l){
  __builtin_amdgcn_global_load_lds(
      (const __attribute__((address_space(1))) unsigned int*)g,
      (__attribute__((address_space(3))) unsigned int*)l,
      16, 0, 0);
}

// grid = 2 x 1024 threads: block 0 builds the Y side (fyg), block 1 the X side
// (fxg). Widened from 256 to 1024 threads to shrink the serial prefix ~4x.
__global__ __launch_bounds__(1024) void k_prep(
    const float* __restrict__ h, const float* __restrict__ Ww,
    const float* __restrict__ Wb, int* __restrict__ meta,
    float* __restrict__ fyg, float* __restrict__ fxg)
{
  __shared__ float partial[16*8];    // [wave][slot]
  __shared__ float par_s[8];
  __shared__ float F[N_FILT*IMG_DIM];        // 64 KiB
  __shared__ int s_lo[64], s_hi[64], s_glo[16], s_ghi[16];
  __shared__ float ssum[16];
  const int t   = threadIdx.x;               // 0..1023
  const int side= blockIdx.x;                // 0=Y, 1=X
  const int wv  = t>>6, ln = t&63;
  float* __restrict__ wout = side ? fxg : fyg;

  // zero-fill this side's weight buffer (packs only overwrite in-band rows)
  {
    float4 z = make_float4(0.f,0.f,0.f,0.f);
    float4* p = (float4*)wout;
    #pragma unroll
    for (int k=0;k<4;++k) p[t + 1024*k] = z;
  }

  // ---- params[j] = h[0] . W_read_w[j] + W_read_b[j] (1 elem per thread) ----
  {
    const float hv = h[t];                   // HDIM == 1024 == blockDim.x
    float s0 = hv*Ww[t];
    float s1 = hv*Ww[HDIM+t];
    float s2 = hv*Ww[2*HDIM+t];
    float s3 = hv*Ww[3*HDIM+t];
    float s4 = hv*Ww[4*HDIM+t];
    #pragma unroll
    for (int o=32;o>0;o>>=1){
      s0+=__shfl_down(s0,o); s1+=__shfl_down(s1,o); s2+=__shfl_down(s2,o);
      s3+=__shfl_down(s3,o); s4+=__shfl_down(s4,o);
    }
    if (ln==0){ partial[wv*8+0]=s0; partial[wv*8+1]=s1; partial[wv*8+2]=s2;
                partial[wv*8+3]=s3; partial[wv*8+4]=s4; }
  }
  __syncthreads();
  if (t<5){
    float s = Wb[t];
    #pragma unroll
    for (int k=0;k<16;++k) s += partial[k*8+t];
    par_s[t] = s;
  }
  __syncthreads();

  const float var   = expf(par_s[2]+1e-8f);
  const float dt    = expf(par_s[3]);
  const float gamma = expf(par_s[4]);
  const float gC = 0.5f*257.f*(par_s[side?0:1]+1.f);  // Y<-par[1], X<-par[0]
  const float d  = dt*(255.f/63.f);
  const float sub= -32.5f*d;
  const float inv2v = 1.f/(2.f*var);
  const float w88v  = 88.f*var;   // band cutoff: e(a)/e(peak) >= exp(-44)

  if (t<64){
    float mu = gC + sub + d*(float)t;
    float astar = fminf(255.f, fmaxf(0.f, rintf(mu)));   // clamped peak
    float t0 = (astar-mu)*(astar-mu);
    float r  = sqrtf(t0 + w88v);
    int lo = (int)ceilf(mu-r); int hi = (int)floorf(mu+r)+1;
    lo = lo<0?0:lo; hi = hi>256?256:hi; if (hi<lo) hi=lo;
    s_lo[t]=lo; s_hi[t]=hi;
  }
  __syncthreads();
  if (t<16){
    int lo=256, hi=0;
    #pragma unroll
    for (int k2=0;k2<4;++k2){ lo=min(lo,s_lo[t*4+k2]); hi=max(hi,s_hi[t*4+k2]); }
    if (hi<lo){lo=0;hi=0;}
    if (side==0){ meta[t]=lo; meta[16+t]=hi; }
    else        { lo &= ~3;  meta[32+t]=lo; meta[48+t]=hi; }  // granule-aligned
    s_glo[t]=lo; s_ghi[t]=hi;
  }
  // F + global sum (16 elems per thread)
  float sum=0.f;
  #pragma unroll
  for (int k=0;k<16;++k){
    int idx=t+1024*k;
    int n=idx>>8, a=idx&255;
    float mu = gC+sub+d*(float)n;
    float dx=(float)a-mu;
    float e=expf(-dx*dx*inv2v);
    F[idx]=e; sum+=e;
  }
  #pragma unroll
  for (int o=32;o>0;o>>=1) sum+=__shfl_down(sum,o);
  if (ln==0) ssum[wv]=sum;
  __syncthreads();
  float stot = 0.f;
  #pragma unroll
  for (int k=0;k<16;++k) stot += ssum[k];    // uniform across threads
  const float sc = (side==0 ? gamma : 1.f)/stot;   // fold gamma into Y side
  #pragma unroll
  for (int k=0;k<16;++k){
    int idx=t+1024*k;
    int n=idx>>8, a=idx&255, g=n>>2;
    int lo=s_glo[g], hi=s_ghi[g];
    if (a>=lo && a<hi) wout[(size_t)((g<<10)+((a-lo)<<2)+(n&3))] = F[idx]*sc;
  }
}

// 2048 blocks: each owns an (x, x_hat) IMAGE PAIR p and quad qq (16 filters).
// 4 waves; wave w owns stage-1 n-group g=qq*4+w (both images) and stage-2
// m-group q=w*4+(lane>>4) (both images).
// Stage 1 = round-8 ring machinery doubled: 4 chunk-slots x (2 rows x 2 imgs),
// depth-3-chunk lookahead (12 DMAs / 12 KB per wave in flight), constant
// clobber-free s_waitcnt vmcnt(12), asm ds_read consume (rule-18 recipe).
// Halves block generations (16->8 per CU) and amortizes all fixed costs x2.
__global__ __launch_bounds__(256, 2) void k_main(
    const float* __restrict__ x, const float* __restrict__ xh,
    const int* __restrict__ meta, const float* __restrict__ fyg,
    const float* __restrict__ fxg, float* __restrict__ out)
{
  __shared__ float POOL[16384];   // 64 KiB
  // stage1 ring: POOL[w*4096 + slot*1024 + {0:A0, 256:B0, 512:A1, 768:B1}]
  // overlay:     TT_A = POOL[0..4095], TT_B = POOL[4096..8191]
  //              TRA  = POOL[8192..9279], TRB = POOL[9472..10559]
  const int bid = blockIdx.x;
  const int lg  = ((bid&7)<<8) | (bid>>3);   // 2048 blocks, bijective
  const int p   = lg>>2, qq = lg&3;
  const int tid = threadIdx.x;
  const int w    = __builtin_amdgcn_readfirstlane(tid>>6);
  const int lane = tid & 63;
  const float* __restrict__ srcA = x  + (size_t)p*IMG_SZ;
  const float* __restrict__ srcB = xh + (size_t)p*IMG_SZ;
  float* __restrict__ dstA = out + (size_t)p*8192 + qq*1024;
  float* __restrict__ dstB = dstA + 4096;

  float accA[4][4], accB[4][4];
  // ---- stage 1: T[n][b] = sum_a FY[n][a]*src[a][b] for BOTH images ----
  {
    const int g  = qq*4 + w;
    const int a0 = __builtin_amdgcn_readfirstlane(meta[g]);
    const int a1 = __builtin_amdgcn_readfirstlane(meta[16+g]);
    const int R  = a1 - a0;                    // rows in band (may be 0)
    const int CC = (R + 1) >> 1;               // 2-row chunks
    const float* const wp = fyg + ((size_t)g<<10);   // [256][4] rel., zero-padded
    const float* const sA = srcA + (lane<<2);
    const float* const sB = srcB + (lane<<2);
    #pragma unroll
    for (int k2=0;k2<4;++k2){
      accA[k2][0]=0.f;accA[k2][1]=0.f;accA[k2][2]=0.f;accA[k2][3]=0.f;
      accB[k2][0]=0.f;accB[k2][1]=0.f;accB[k2][2]=0.f;accB[k2][3]=0.f;
    }

#define DMA4(ch) do{ const int _c=(ch); const int _r0=a0+2*_c; \
    float* const _b = &POOL[(w<<12) + ((_c&3)<<10)]; \
    gl_lds16(sA + ((size_t)min(_r0,  255)<<8), _b); \
    gl_lds16(sB + ((size_t)min(_r0,  255)<<8), _b+256); \
    gl_lds16(sA + ((size_t)min(_r0+1,255)<<8), _b+512); \
    gl_lds16(sB + ((size_t)min(_r0+1,255)<<8), _b+768); }while(0)
#define FMAROW(ACC,W,T) do{ \
    ACC[0][0]=fmaf(W.x,T.x,ACC[0][0]); ACC[0][1]=fmaf(W.x,T.y,ACC[0][1]); \
    ACC[0][2]=fmaf(W.x,T.z,ACC[0][2]); ACC[0][3]=fmaf(W.x,T.w,ACC[0][3]); \
    ACC[1][0]=fmaf(W.y,T.x,ACC[1][0]); ACC[1][1]=fmaf(W.y,T.y,ACC[1][1]); \
    ACC[1][2]=fmaf(W.y,T.z,ACC[1][2]); ACC[1][3]=fmaf(W.y,T.w,ACC[1][3]); \
    ACC[2][0]=fmaf(W.z,T.x,ACC[2][0]); ACC[2][1]=fmaf(W.z,T.y,ACC[2][1]); \
    ACC[2][2]=fmaf(W.z,T.z,ACC[2][2]); ACC[2][3]=fmaf(W.z,T.w,ACC[2][3]); \
    ACC[3][0]=fmaf(W.w,T.x,ACC[3][0]); ACC[3][1]=fmaf(W.w,T.y,ACC[3][1]); \
    ACC[3][2]=fmaf(W.w,T.z,ACC[3][2]); ACC[3][3]=fmaf(W.w,T.w,ACC[3][3]); }while(0)

    if (R > 0){
      // ring prologue: 3 chunks (12 DMAs, 12 KB) in flight
      DMA4(0); DMA4(1); DMA4(2);
      #pragma unroll 1
      for (int c=0; c<CC; ++c){
        DMA4(c+3);                             // 16 outstanding after issue
        __builtin_amdgcn_sched_barrier(0);
        asm volatile("s_waitcnt vmcnt(12)");   // chunk c landed; 3 in flight
        __builtin_amdgcn_sched_barrier(0);
        f32x4 tA0,tB0,tA1,tB1;
        lds_float* l0 = (lds_float*)&POOL[(w<<12) + ((c&3)<<10) + (lane<<2)];
        asm volatile("ds_read_b128 %0, %1"             : "=&v"(tA0) : "v"(l0));
        asm volatile("ds_read_b128 %0, %1 offset:1024" : "=&v"(tB0) : "v"(l0));
        asm volatile("ds_read_b128 %0, %1 offset:2048" : "=&v"(tA1) : "v"(l0));
        asm volatile("ds_read_b128 %0, %1 offset:3072" : "=&v"(tB1) : "v"(l0));
        // relative rows: 2c <= 255; 2c+1 <= R <= 256 -> clamp; zero-fill beyond band
        const f32x4 w0 = ((const f32x4*)wp)[min(2*c,  255)];   // uniform s_load
        const f32x4 w1 = ((const f32x4*)wp)[min(2*c+1,255)];
        asm volatile("s_waitcnt lgkmcnt(0)");
        __builtin_amdgcn_sched_barrier(0);
        FMAROW(accA,w0,tA0); FMAROW(accB,w0,tB0);
        FMAROW(accA,w1,tA1); FMAROW(accB,w1,tB1);
      }
      asm volatile("s_waitcnt vmcnt(0)");      // per-wave drain before overlay
    }
#undef DMA4
  }
  __syncthreads();                             // all waves' DMAs retired
  // b128 writes into TT_A / TT_B, granule-XOR swizzle (lane ^ n)
  #pragma unroll
  for (int k2=0;k2<4;++k2){
    const int n = w*4 + k2;                    // wave-uniform row (0..15)
    float4 va; va.x=accA[k2][0]; va.y=accA[k2][1]; va.z=accA[k2][2]; va.w=accA[k2][3];
    float4 vb; vb.x=accB[k2][0]; vb.y=accB[k2][1]; vb.z=accB[k2][2]; vb.w=accB[k2][3];
    *(float4*)&POOL[       (n<<8) + ((lane ^ n)<<2)] = va;
    *(float4*)&POOL[4096 + (n<<8) + ((lane ^ n)<<2)] = vb;
  }
  __syncthreads();

  // ---- stage 2: out[n][m] = sum_b T[n][b]*FX[m][b]; lane = cc*16 + nl ----
  const int nl = lane & 15;
  const int cc = lane >> 4;
  const int q  = w*4 + cc;                     // one m-group of 4 per (wave,cc)
  const int lo4 = meta[32+q];
  const int hi  = meta[48+q];
  int ngu = (hi - lo4 + 3) >> 2;
  ngu = max(ngu, __shfl_xor(ngu,16));          // wave-uniform trip count
  ngu = max(ngu, __shfl_xor(ngu,32));          // (overrun iters: zero weights)
  const int u0  = lo4 >> 2;
  const float* wq = fxg + ((size_t)q<<10);     // [256][4] rows packed from lo4
  float oA0=0.f,oA1=0.f,oA2=0.f,oA3=0.f;
  float oB0=0.f,oB1=0.f,oB2=0.f,oB3=0.f;
  #pragma unroll 2
  for (int it=0; it<ngu; it+=2){
    const int uA_ = min(u0+it,   63);
    const int uB_ = min(u0+it+1, 63);
    const float4 tA0 = *(const float4*)&POOL[       (nl<<8) + ((uA_^nl)<<2)];
    const float4 tA1 = *(const float4*)&POOL[       (nl<<8) + ((uB_^nl)<<2)];
    const float4 tB0 = *(const float4*)&POOL[4096 + (nl<<8) + ((uA_^nl)<<2)];
    const float4 tB1 = *(const float4*)&POOL[4096 + (nl<<8) + ((uB_^nl)<<2)];
    const float4 a0w = *(const float4*)(wq + it*16);      // shared by A and B
    const float4 a1w = *(const float4*)(wq + it*16 + 4);
    const float4 a2w = *(const float4*)(wq + it*16 + 8);
    const float4 a3w = *(const float4*)(wq + it*16 + 12);
    const float4 b0w = *(const float4*)(wq + it*16 + 16);
    const float4 b1w = *(const float4*)(wq + it*16 + 20);
    const float4 b2w = *(const float4*)(wq + it*16 + 24);
    const float4 b3w = *(const float4*)(wq + it*16 + 28);
    oA0=fmaf(tA0.x,a0w.x,fmaf(tA0.y,a1w.x,fmaf(tA0.z,a2w.x,fmaf(tA0.w,a3w.x,oA0))));
    oA1=fmaf(tA0.x,a0w.y,fmaf(tA0.y,a1w.y,fmaf(tA0.z,a2w.y,fmaf(tA0.w,a3w.y,oA1))));
    oA2=fmaf(tA0.x,a0w.z,fmaf(tA0.y,a1w.z,fmaf(tA0.z,a2w.z,fmaf(tA0.w,a3w.z,oA2))));
    oA3=fmaf(tA0.x,a0w.w,fmaf(tA0.y,a1w.w,fmaf(tA0.z,a2w.w,fmaf(tA0.w,a3w.w,oA3))));
    oB0=fmaf(tB0.x,a0w.x,fmaf(tB0.y,a1w.x,fmaf(tB0.z,a2w.x,fmaf(tB0.w,a3w.x,oB0))));
    oB1=fmaf(tB0.x,a0w.y,fmaf(tB0.y,a1w.y,fmaf(tB0.z,a2w.y,fmaf(tB0.w,a3w.y,oB1))));
    oB2=fmaf(tB0.x,a0w.z,fmaf(tB0.y,a1w.z,fmaf(tB0.z,a2w.z,fmaf(tB0.w,a3w.z,oB2))));
    oB3=fmaf(tB0.x,a0w.w,fmaf(tB0.y,a1w.w,fmaf(tB0.z,a2w.w,fmaf(tB0.w,a3w.w,oB3))));
    if (it+1 < ngu){
      oA0=fmaf(tA1.x,b0w.x,fmaf(tA1.y,b1w.x,fmaf(tA1.z,b2w.x,fmaf(tA1.w,b3w.x,oA0))));
      oA1=fmaf(tA1.x,b0w.y,fmaf(tA1.y,b1w.y,fmaf(tA1.z,b2w.y,fmaf(tA1.w,b3w.y,oA1))));
      oA2=fmaf(tA1.x,b0w.z,fmaf(tA1.y,b1w.z,fmaf(tA1.z,b2w.z,fmaf(tA1.w,b3w.z,oA2))));
      oA3=fmaf(tA1.x,b0w.w,fmaf(tA1.y,b1w.w,fmaf(tA1.z,b2w.w,fmaf(tA1.w,b3w.w,oA3))));
      oB0=fmaf(tB1.x,b0w.x,fmaf(tB1.y,b1w.x,fmaf(tB1.z,b2w.x,fmaf(tB1.w,b3w.x,oB0))));
      oB1=fmaf(tB1.x,b0w.y,fmaf(tB1.y,b1w.y,fmaf(tB1.z,b2w.y,fmaf(tB1.w,b3w.y,oB1))));
      oB2=fmaf(tB1.x,b0w.z,fmaf(tB1.y,b1w.z,fmaf(tB1.z,b2w.z,fmaf(tB1.w,b3w.z,oB2))));
      oB3=fmaf(tB1.x,b0w.w,fmaf(tB1.y,b1w.w,fmaf(tB1.z,b2w.w,fmaf(tB1.w,b3w.w,oB3))));
    }
  }
  // transpose bufs live at POOL[8192..] (dead ring space) — disjoint from TT,
  // so no barrier needed between stage-2 TT reads and these writes.
  {
    const int m0 = q*4;
    POOL[8192 + nl*68 + m0 + 0] = oA0; POOL[8192 + nl*68 + m0 + 1] = oA1;
    POOL[8192 + nl*68 + m0 + 2] = oA2; POOL[8192 + nl*68 + m0 + 3] = oA3;
    POOL[9472 + nl*68 + m0 + 0] = oB0; POOL[9472 + nl*68 + m0 + 1] = oB1;
    POOL[9472 + nl*68 + m0 + 2] = oB2; POOL[9472 + nl*68 + m0 + 3] = oB3;
  }
  __syncthreads();
  {
    const int f = tid*4;
    const int n = f>>6, m = f&63;
    *(float4*)(dstA+f) = *(const float4*)&POOL[8192 + n*68 + m];
    *(float4*)(dstB+f) = *(const float4*)&POOL[9472 + n*68 + m];
  }
#undef FMAROW
}

extern "C" void kernel_launch(void* const* d_in, const int* in_sizes, int n_in,
                              void* d_out, int out_size, void* d_ws, size_t ws_size,
                              hipStream_t stream)
{
  const float* x  = (const float*)d_in[0];
  const float* xh = (const float*)d_in[1];
  const float* h  = (const float*)d_in[2];   // only row 0 is used
  const float* Ww = (const float*)d_in[3];
  const float* Wb = (const float*)d_in[4];
  float* out = (float*)d_out;

  int*   meta = (int*)d_ws;
  float* fyg  = (float*)((char*)d_ws + 256);
  float* fxg  = (float*)((char*)d_ws + 256 + 65536);

  k_prep<<<2, 1024, 0, stream>>>(h, Ww, Wb, meta, fyg, fxg);
  k_main<<<4*NBATCH, 256, 0, stream>>>(x, xh, meta, fyg, fxg, out);
}